// Round 1
// baseline (214.481 us; speedup 1.0000x reference)
//
#include <hip/hip_runtime.h>

#define N_CLS 8192
#define DIM   2048
#define BM    128
#define BK    32
#define NB    (N_CLS / BM)   // 64 block-rows/cols

typedef unsigned short u16;
typedef __attribute__((ext_vector_type(4))) float f32x4;
typedef __bf16 bf16x8 __attribute__((ext_vector_type(8)));

// float -> bf16 bits, round-to-nearest-even (inputs are finite)
__device__ __forceinline__ unsigned f2bf(float f) {
    union { float f; unsigned u; } a; a.f = f;
    return (a.u + 0x7fffu + ((a.u >> 16) & 1u)) >> 16;
}
__device__ __forceinline__ unsigned pack2(float lo, float hi) {
    return (f2bf(lo) & 0xffffu) | (f2bf(hi) << 16);
}

// async global->LDS, 16B per lane; LDS dest is wave-uniform base + lane*16
__device__ __forceinline__ void load16(const u16* g, u16* l) {
    __builtin_amdgcn_global_load_lds(
        (const __attribute__((address_space(1))) void*)g,
        (__attribute__((address_space(3))) void*)l, 16, 0, 0);
}

// ---------------- kernel 1: row L2-normalize, cast to bf16 ----------------
__global__ __launch_bounds__(256) void normalize_rows(const float* __restrict__ x,
                                                      u16* __restrict__ xnb) {
    const int row = blockIdx.x;
    const int t = threadIdx.x;
    const float4* xr = reinterpret_cast<const float4*>(x + (size_t)row * DIM);
    float4 v0 = xr[t * 2 + 0];
    float4 v1 = xr[t * 2 + 1];
    float s = v0.x*v0.x + v0.y*v0.y + v0.z*v0.z + v0.w*v0.w
            + v1.x*v1.x + v1.y*v1.y + v1.z*v1.z + v1.w*v1.w;
#pragma unroll
    for (int off = 32; off > 0; off >>= 1) s += __shfl_down(s, off);
    __shared__ float red[4];
    if ((t & 63) == 0) red[t >> 6] = s;
    __syncthreads();
    const float total = red[0] + red[1] + red[2] + red[3];
    const float inv = 1.0f / fmaxf(sqrtf(total), 1e-12f);  // matches F.normalize eps
    uint4 o;
    o.x = pack2(v0.x * inv, v0.y * inv);
    o.y = pack2(v0.z * inv, v0.w * inv);
    o.z = pack2(v1.x * inv, v1.y * inv);
    o.w = pack2(v1.z * inv, v1.w * inv);
    *reinterpret_cast<uint4*>(xnb + (size_t)row * DIM + t * 8) = o;
}

// ------- kernel 2: 128x128 bf16 MFMA tile of xn·xnT, fused exp-sum -------
// Upper-triangular blocks only (bi <= bj); off-diagonal weighted 2x.
__global__ __launch_bounds__(256) void gram_exp(const u16* __restrict__ xnb,
                                                float* __restrict__ partials) {
    const int bj = blockIdx.x, bi = blockIdx.y;
    const int bid = bi * NB + bj;
    const int tid = threadIdx.x;
    if (bj < bi) {                      // symmetric half: skip, but write partial
        if (tid == 0) partials[bid] = 0.0f;
        return;
    }

    __shared__ u16 As[BM * BK];         // 8 KiB, row-major [128][32]
    __shared__ u16 Bs[BM * BK];         // 8 KiB
    __shared__ float red[4];

    const int lane = tid & 63, wid = tid >> 6;
    const int wr = wid >> 1, wc = wid & 1;   // wave -> 64x64 quadrant

    // staging: tile = 8 chunks x 1024B; wave w stages chunks {2w, 2w+1}
    const int c0 = wid * 2, c1 = c0 + 1;
    const int srow = lane >> 2;              // row within 16-row chunk
    const int scol = (lane & 3) * 8;         // k-col (elements)
    const size_t aoff0 = (size_t)(bi * BM + c0 * 16 + srow) * DIM + scol;
    const size_t aoff1 = (size_t)(bi * BM + c1 * 16 + srow) * DIM + scol;
    const size_t boff0 = (size_t)(bj * BM + c0 * 16 + srow) * DIM + scol;
    const size_t boff1 = (size_t)(bj * BM + c1 * 16 + srow) * DIM + scol;
    u16* ldsA0 = &As[c0 * 512];
    u16* ldsA1 = &As[c1 * 512];
    u16* ldsB0 = &Bs[c0 * 512];
    u16* ldsB1 = &Bs[c1 * 512];

    f32x4 acc[4][4];
#pragma unroll
    for (int m = 0; m < 4; ++m)
#pragma unroll
        for (int n = 0; n < 4; ++n)
            acc[m][n] = (f32x4){0.f, 0.f, 0.f, 0.f};

    // A-frag: row = lane&15, k = (lane>>4)*8..+8  (HW-verified layout)
    const int afrag = (wr * 64 + (lane & 15)) * BK + (lane >> 4) * 8;
    const int bfrag = (wc * 64 + (lane & 15)) * BK + (lane >> 4) * 8;

    for (int k0 = 0; k0 < DIM; k0 += BK) {
        load16(xnb + aoff0 + k0, ldsA0);
        load16(xnb + aoff1 + k0, ldsA1);
        load16(xnb + boff0 + k0, ldsB0);
        load16(xnb + boff1 + k0, ldsB1);
        __syncthreads();                      // drains vmcnt before barrier
        bf16x8 af[4], bg[4];
#pragma unroll
        for (int m = 0; m < 4; ++m)
            af[m] = *reinterpret_cast<const bf16x8*>(&As[afrag + m * 16 * BK]);
#pragma unroll
        for (int n = 0; n < 4; ++n)
            bg[n] = *reinterpret_cast<const bf16x8*>(&Bs[bfrag + n * 16 * BK]);
#pragma unroll
        for (int m = 0; m < 4; ++m)
#pragma unroll
            for (int n = 0; n < 4; ++n)
                acc[m][n] = __builtin_amdgcn_mfma_f32_16x16x32_bf16(
                    af[m], bg[n], acc[m][n], 0, 0, 0);
        __syncthreads();
    }

    // fused epilogue: sum exp(-max(2 - 2g, 0)) over the tile (rows unit-norm)
    float s = 0.f;
#pragma unroll
    for (int m = 0; m < 4; ++m)
#pragma unroll
        for (int n = 0; n < 4; ++n)
#pragma unroll
            for (int r = 0; r < 4; ++r) {
                float g = acc[m][n][r];
                float d2 = fmaxf(2.0f - 2.0f * g, 0.0f);
                s += __expf(-d2);
            }
#pragma unroll
    for (int off = 32; off > 0; off >>= 1) s += __shfl_down(s, off);
    if (lane == 0) red[wid] = s;
    __syncthreads();
    if (tid == 0) {
        float tot = red[0] + red[1] + red[2] + red[3];
        partials[bid] = (bi == bj) ? tot : 2.0f * tot;
    }
}

// ---------------- kernel 3: reduce partials, scale ----------------
__global__ __launch_bounds__(256) void finalize(const float* __restrict__ partials,
                                                float* __restrict__ out) {
    float s = 0.f;
    for (int i = threadIdx.x; i < NB * NB; i += 256) s += partials[i];
#pragma unroll
    for (int off = 32; off > 0; off >>= 1) s += __shfl_down(s, off);
    __shared__ float red[4];
    if ((threadIdx.x & 63) == 0) red[threadIdx.x >> 6] = s;
    __syncthreads();
    if (threadIdx.x == 0)
        out[0] = (red[0] + red[1] + red[2] + red[3]) *
                 (1.0f / (8191.0f * 8192.0f));   // / ((N-1) * N), exact in fp32
}

extern "C" void kernel_launch(void* const* d_in, const int* in_sizes, int n_in,
                              void* d_out, int out_size, void* d_ws, size_t ws_size,
                              hipStream_t stream) {
    const float* x = (const float*)d_in[0];
    float* out = (float*)d_out;
    // ws layout: [0, 32MB) bf16 normalized matrix; then 4096 fp32 partials
    u16* xnb = (u16*)d_ws;
    float* partials = (float*)((char*)d_ws + (size_t)N_CLS * DIM * sizeof(u16));

    normalize_rows<<<N_CLS, 256, 0, stream>>>(x, xnb);
    dim3 grid(NB, NB);
    gram_exp<<<grid, 256, 0, stream>>>(xnb, partials);
    finalize<<<1, 256, 0, stream>>>(partials, out);
}

// Round 2
// 187.003 us; speedup vs baseline: 1.1469x; 1.1469x over previous
//
#include <hip/hip_runtime.h>

#define N_CLS 8192
#define DIM   2048
#define BK    64
#define NBT   32            // 8192/256 tile grid
#define NTILES 528          // NBT*(NBT+1)/2
#define NFULL 512           // full 256x256 tiles in launch 1
#define NT    (DIM / BK)    // 32 K-tiles

typedef unsigned short u16;
typedef __attribute__((ext_vector_type(16))) float f32x16;
typedef __bf16 bf16x8 __attribute__((ext_vector_type(8)));

__device__ __forceinline__ unsigned f2bf(float f) {
    union { float f; unsigned u; } a; a.f = f;
    return (a.u + 0x7fffu + ((a.u >> 16) & 1u)) >> 16;
}
__device__ __forceinline__ unsigned pack2(float lo, float hi) {
    return (f2bf(lo) & 0xffffu) | (f2bf(hi) << 16);
}

__device__ __forceinline__ void load16(const u16* g, u16* l) {
    __builtin_amdgcn_global_load_lds(
        (const __attribute__((address_space(1))) void*)g,
        (__attribute__((address_space(3))) void*)l, 16, 0, 0);
}

template <int N> __device__ __forceinline__ void waitcnt_vm() {
    if constexpr (N == 0)      asm volatile("s_waitcnt vmcnt(0)" ::: "memory");
    else if constexpr (N == 6) asm volatile("s_waitcnt vmcnt(6)" ::: "memory");
    else if constexpr (N == 8) asm volatile("s_waitcnt vmcnt(8)" ::: "memory");
}
__device__ __forceinline__ void hard_barrier() {
    __builtin_amdgcn_sched_barrier(0);
    __builtin_amdgcn_s_barrier();
    __builtin_amdgcn_sched_barrier(0);
}

// ---------------- kernel 1: row L2-normalize, cast to bf16 ----------------
__global__ __launch_bounds__(256) void normalize_rows(const float* __restrict__ x,
                                                      u16* __restrict__ xnb) {
    const int row = blockIdx.x;
    const int t = threadIdx.x;
    const float4* xr = reinterpret_cast<const float4*>(x + (size_t)row * DIM);
    float4 v0 = xr[t * 2 + 0];
    float4 v1 = xr[t * 2 + 1];
    float s = v0.x*v0.x + v0.y*v0.y + v0.z*v0.z + v0.w*v0.w
            + v1.x*v1.x + v1.y*v1.y + v1.z*v1.z + v1.w*v1.w;
#pragma unroll
    for (int off = 32; off > 0; off >>= 1) s += __shfl_down(s, off);
    __shared__ float red[4];
    if ((t & 63) == 0) red[t >> 6] = s;
    __syncthreads();
    const float total = red[0] + red[1] + red[2] + red[3];
    const float inv = 1.0f / fmaxf(sqrtf(total), 1e-12f);
    uint4 o;
    o.x = pack2(v0.x * inv, v0.y * inv);
    o.y = pack2(v0.z * inv, v0.w * inv);
    o.z = pack2(v1.x * inv, v1.y * inv);
    o.w = pack2(v1.z * inv, v1.w * inv);
    *reinterpret_cast<uint4*>(xnb + (size_t)row * DIM + t * 8) = o;
}

// ---- kernel 2: deep-pipelined 256xBN bf16 MFMA gram tile + fused exp-sum ----
// NFR=2: 256x256 tiles (blocks 0..511). NFR=1: 256x128 half-tiles of tiles 512..527.
template <int NFR>
__global__ __launch_bounds__(512) void gram_tile(const u16* __restrict__ xnb,
                                                 float* __restrict__ partials) {
    constexpr int WN     = NFR * 32;          // per-wave N
    constexpr int A_SLOT = 256 * BK;          // 16384 elems (32 KB)
    constexpr int B_SLOT = NFR * 128 * BK;    // 16384 / 8192 elems
    constexpr int CALLS  = 4 + 2 * NFR;       // global_load_lds per wave per K-tile

    __shared__ __align__(16) u16 As[2 * A_SLOT];
    __shared__ __align__(16) u16 Bs[2 * B_SLOT];
    __shared__ float red[8];

    int lin, colHalf;
    if constexpr (NFR == 2) { lin = blockIdx.x; colHalf = 0; }
    else { lin = NFULL + (blockIdx.x >> 1); colHalf = blockIdx.x & 1; }
    // triangle inverse: lin -> (bi, bj), bi <= bj
    int bi = 0, rem = lin;
    while (rem >= NBT - bi) { rem -= NBT - bi; ++bi; }
    const int bj = bi + rem;

    const int tid = threadIdx.x;
    const int lane = tid & 63, wid = tid >> 6;
    const int wr = wid >> 2, wc = wid & 3;    // wave grid 2 x 4

    // ---- staging addresses (pre-swizzled global source; linear LDS dest) ----
    const int srow = tid >> 3;                         // 0..63 within a 64-row call
    const int schunk = ((tid & 7) ^ (srow & 7)) * 8;   // involutive chunk XOR
    const u16* gA = xnb + (size_t)(bi * 256 + srow) * DIM + schunk;
    const u16* gB = xnb + (size_t)(bj * 256 + colHalf * 128 + srow) * DIM + schunk;

    auto stageA = [&](int tt, int s) {
#pragma unroll
        for (int q = 0; q < 4; ++q)
            load16(gA + (size_t)(q * 64) * DIM + tt * BK,
                   &As[s * A_SLOT + q * 4096 + wid * 512]);
    };
    auto stageB = [&](int tt, int s) {
#pragma unroll
        for (int q = 0; q < 2 * NFR; ++q)
            load16(gB + (size_t)(q * 64) * DIM + tt * BK,
                   &Bs[s * B_SLOT + q * 4096 + wid * 512]);
    };

    // ---- fragment read addressing (swizzled) ----
    const int lr = lane & 31, hi = lane >> 5, l7 = lane & 7;
    int coff[4];
#pragma unroll
    for (int kk = 0; kk < 4; ++kk) coff[kk] = ((kk * 2 + hi) ^ l7) << 3;
    const int arow = (wr * 128 + lr) * BK;   // + m*32*BK
    const int brow = (wc * WN + lr) * BK;    // + n*32*BK

    f32x16 acc[4][NFR];
#pragma unroll
    for (int m = 0; m < 4; ++m)
#pragma unroll
        for (int n = 0; n < NFR; ++n)
#pragma unroll
            for (int r = 0; r < 16; ++r) acc[m][n][r] = 0.0f;

    // ---- prologue: stage tiles 0,1; retire tile 0 ----
    stageA(0, 0); stageB(0, 0);
    stageA(1, 1); stageB(1, 1);
    waitcnt_vm<CALLS>();
    hard_barrier();

    for (int t = 0; t < NT; ++t) {
        const int sa = (t & 1) * A_SLOT;
        const int sb = (t & 1) * B_SLOT;

        bf16x8 a0[4], a1[4], b0[NFR], b1[NFR];
#pragma unroll
        for (int m = 0; m < 4; ++m) {
            a0[m] = *reinterpret_cast<const bf16x8*>(&As[sa + arow + m * 32 * BK + coff[0]]);
            a1[m] = *reinterpret_cast<const bf16x8*>(&As[sa + arow + m * 32 * BK + coff[1]]);
        }
#pragma unroll
        for (int n = 0; n < NFR; ++n) {
            b0[n] = *reinterpret_cast<const bf16x8*>(&Bs[sb + brow + n * 32 * BK + coff[0]]);
            b1[n] = *reinterpret_cast<const bf16x8*>(&Bs[sb + brow + n * 32 * BK + coff[1]]);
        }
        __builtin_amdgcn_s_setprio(1);
#pragma unroll
        for (int m = 0; m < 4; ++m)
#pragma unroll
            for (int n = 0; n < NFR; ++n)
                acc[m][n] = __builtin_amdgcn_mfma_f32_32x32x16_bf16(a0[m], b0[n], acc[m][n], 0, 0, 0);
#pragma unroll
        for (int m = 0; m < 4; ++m)
#pragma unroll
            for (int n = 0; n < NFR; ++n)
                acc[m][n] = __builtin_amdgcn_mfma_f32_32x32x16_bf16(a1[m], b1[n], acc[m][n], 0, 0, 0);
        __builtin_amdgcn_s_setprio(0);

        bf16x8 a2[4], a3[4], b2[NFR], b3[NFR];
#pragma unroll
        for (int m = 0; m < 4; ++m) {
            a2[m] = *reinterpret_cast<const bf16x8*>(&As[sa + arow + m * 32 * BK + coff[2]]);
            a3[m] = *reinterpret_cast<const bf16x8*>(&As[sa + arow + m * 32 * BK + coff[3]]);
        }
#pragma unroll
        for (int n = 0; n < NFR; ++n) {
            b2[n] = *reinterpret_cast<const bf16x8*>(&Bs[sb + brow + n * 32 * BK + coff[2]]);
            b3[n] = *reinterpret_cast<const bf16x8*>(&Bs[sb + brow + n * 32 * BK + coff[3]]);
        }
        // all reads of this slot complete (all waves) -> slot safe to overwrite
        asm volatile("s_waitcnt lgkmcnt(0)" ::: "memory");
        hard_barrier();

        const bool st = (t + 2 < NT);
        if (st) stageA(t + 2, t & 1);
        __builtin_amdgcn_s_setprio(1);
#pragma unroll
        for (int m = 0; m < 4; ++m)
#pragma unroll
            for (int n = 0; n < NFR; ++n)
                acc[m][n] = __builtin_amdgcn_mfma_f32_32x32x16_bf16(a2[m], b2[n], acc[m][n], 0, 0, 0);
        __builtin_amdgcn_s_setprio(0);
        if (st) stageB(t + 2, t & 1);
        __builtin_amdgcn_s_setprio(1);
#pragma unroll
        for (int m = 0; m < 4; ++m)
#pragma unroll
            for (int n = 0; n < NFR; ++n)
                acc[m][n] = __builtin_amdgcn_mfma_f32_32x32x16_bf16(a3[m], b3[n], acc[m][n], 0, 0, 0);
        __builtin_amdgcn_s_setprio(0);

        if (t < NT - 1) {
            // retire tile t+1 (leave tile t+2's CALLS loads in flight)
            if (st) waitcnt_vm<CALLS>(); else waitcnt_vm<0>();
            hard_barrier();
        }
    }

    // ---- epilogue: sum exp(-max(2-2g,0)); layout-agnostic over acc ----
    float s = 0.0f;
#pragma unroll
    for (int m = 0; m < 4; ++m)
#pragma unroll
        for (int n = 0; n < NFR; ++n)
#pragma unroll
            for (int r = 0; r < 16; ++r) {
                float g = acc[m][n][r];
                s += __expf(-fmaxf(2.0f - 2.0f * g, 0.0f));
            }
#pragma unroll
    for (int off = 32; off > 0; off >>= 1) s += __shfl_down(s, off);
    if (lane == 0) red[wid] = s;
    __syncthreads();
    if (tid == 0) {
        float tot = 0.0f;
#pragma unroll
        for (int w = 0; w < 8; ++w) tot += red[w];
        partials[blockIdx.x] = (bi == bj ? 1.0f : 2.0f) * tot;
    }
}

// ---------------- kernel 3: reduce partials, scale ----------------
__global__ __launch_bounds__(256) void finalize(const float* __restrict__ partials,
                                                float* __restrict__ out) {
    float s = 0.f;
    for (int i = threadIdx.x; i < NFULL + 32; i += 256) s += partials[i];
#pragma unroll
    for (int off = 32; off > 0; off >>= 1) s += __shfl_down(s, off);
    __shared__ float red[4];
    if ((threadIdx.x & 63) == 0) red[threadIdx.x >> 6] = s;
    __syncthreads();
    if (threadIdx.x == 0)
        out[0] = (red[0] + red[1] + red[2] + red[3]) *
                 (1.0f / (8191.0f * 8192.0f));
}

extern "C" void kernel_launch(void* const* d_in, const int* in_sizes, int n_in,
                              void* d_out, int out_size, void* d_ws, size_t ws_size,
                              hipStream_t stream) {
    const float* x = (const float*)d_in[0];
    float* out = (float*)d_out;
    u16* xnb = (u16*)d_ws;                                   // 32 MB
    float* partials = (float*)((char*)d_ws + (size_t)N_CLS * DIM * sizeof(u16));

    normalize_rows<<<N_CLS, 256, 0, stream>>>(x, xnb);
    gram_tile<2><<<NFULL, 512, 0, stream>>>(xnb, partials);
    gram_tile<1><<<32, 512, 0, stream>>>(xnb, partials + NFULL);
    finalize<<<1, 256, 0, stream>>>(partials, out);
}

// Round 3
// 100.540 us; speedup vs baseline: 2.1333x; 1.8600x over previous
//
#include <hip/hip_runtime.h>

#define N_CLS 8192
#define DIMB  2048          // bytes per row (fp8: 1 B/elem)
#define BKB   128           // K-tile in bytes/elems
#define NBT   32            // 8192/256
#define NFULL 512           // full 256x256 tiles in launch 1
#define NT    (DIMB / BKB)  // 16 K-tiles

typedef __attribute__((ext_vector_type(16))) float f32x16;
typedef __attribute__((ext_vector_type(8)))  int   i32x8;

__device__ __forceinline__ void load16(const char* g, char* l) {
    __builtin_amdgcn_global_load_lds(
        (const __attribute__((address_space(1))) void*)g,
        (__attribute__((address_space(3))) void*)l, 16, 0, 0);
}
template <int N> __device__ __forceinline__ void waitcnt_vm() {
    if constexpr (N == 0)      asm volatile("s_waitcnt vmcnt(0)" ::: "memory");
    else if constexpr (N == 6) asm volatile("s_waitcnt vmcnt(6)" ::: "memory");
    else if constexpr (N == 8) asm volatile("s_waitcnt vmcnt(8)" ::: "memory");
}
__device__ __forceinline__ void hard_barrier() {
    __builtin_amdgcn_sched_barrier(0);
    __builtin_amdgcn_s_barrier();
    __builtin_amdgcn_sched_barrier(0);
}

// ------------- kernel 1: row L2-normalize, scale x16, cast to fp8 e4m3 -------------
__global__ __launch_bounds__(256) void normalize_rows(const float* __restrict__ x,
                                                      char* __restrict__ xq) {
    const int row = blockIdx.x;
    const int t = threadIdx.x;
    const float4* xr = reinterpret_cast<const float4*>(x + (size_t)row * 2048);
    float4 v0 = xr[t * 2 + 0];
    float4 v1 = xr[t * 2 + 1];
    float s = v0.x*v0.x + v0.y*v0.y + v0.z*v0.z + v0.w*v0.w
            + v1.x*v1.x + v1.y*v1.y + v1.z*v1.z + v1.w*v1.w;
#pragma unroll
    for (int off = 32; off > 0; off >>= 1) s += __shfl_down(s, off);
    __shared__ float red[4];
    if ((t & 63) == 0) red[t >> 6] = s;
    __syncthreads();
    const float total = red[0] + red[1] + red[2] + red[3];
    const float inv = 1.0f / fmaxf(sqrtf(total), 1e-12f);
    const float s16 = inv * 16.0f;     // keep values in e4m3 normal range
    int w0 = __builtin_amdgcn_cvt_pk_fp8_f32(v0.x * s16, v0.y * s16, 0, false);
    w0     = __builtin_amdgcn_cvt_pk_fp8_f32(v0.z * s16, v0.w * s16, w0, true);
    int w1 = __builtin_amdgcn_cvt_pk_fp8_f32(v1.x * s16, v1.y * s16, 0, false);
    w1     = __builtin_amdgcn_cvt_pk_fp8_f32(v1.z * s16, v1.w * s16, w1, true);
    int2 o = make_int2(w0, w1);
    *reinterpret_cast<int2*>(xq + (size_t)row * DIMB + t * 8) = o;
}

// read one 32-byte (K=64-half) fp8 fragment from a swizzled LDS row
__device__ __forceinline__ i32x8 rdfrag(const char* rowp, int cc, int swz) {
    int4 lo = *reinterpret_cast<const int4*>(rowp + (((cc    ) ^ swz) << 4));
    int4 hi = *reinterpret_cast<const int4*>(rowp + (((cc + 1) ^ swz) << 4));
    i32x8 r;
    r[0] = lo.x; r[1] = lo.y; r[2] = lo.z; r[3] = lo.w;
    r[4] = hi.x; r[5] = hi.y; r[6] = hi.z; r[7] = hi.w;
    return r;
}

// ---- kernel 2: deep-pipelined 256xBN MX-fp8 gram tile + fused exp-sum ----
template <int NFR>   // NFR=2: 256x256 tiles; NFR=1: 256x128 half-tiles of the last 16 tiles
__global__ __launch_bounds__(512, 2) void gram_tile(const char* __restrict__ xq,
                                                    float* __restrict__ partials) {
    constexpr int WN     = NFR * 32;
    constexpr int A_SLOT = 256 * BKB;          // 32 KiB
    constexpr int B_SLOT = NFR * 128 * BKB;    // 32 / 16 KiB
    constexpr int CALLS  = 4 + 2 * NFR;        // global_load_lds per wave per K-tile

    __shared__ __align__(16) char As[2 * A_SLOT];
    __shared__ __align__(16) char Bs[2 * B_SLOT];
    __shared__ float red[8];

    int lin, colHalf;
    if constexpr (NFR == 2) { lin = blockIdx.x; colHalf = 0; }
    else { lin = NFULL + (blockIdx.x >> 1); colHalf = blockIdx.x & 1; }
    int bi = 0, rem = lin;
    while (rem >= NBT - bi) { rem -= NBT - bi; ++bi; }
    const int bj = bi + rem;

    const int tid = threadIdx.x;
    const int lane = tid & 63, wid = tid >> 6;
    const int wr = wid >> 2, wc = wid & 3;     // wave grid 2 x 4

    // ---- staging (pre-swizzled global source; linear LDS dest) ----
    const int srow = lane >> 3;                      // 0..7 within an 8-row call
    const int gch  = ((lane & 7) ^ srow) << 4;       // involutive 16B-chunk XOR
    const char* gA = xq + (size_t)(bi * 256 + wid * 32 + srow) * DIMB + gch;
    const char* gB = xq + (size_t)(bj * 256 + colHalf * 128 +
                                   wid * (NFR == 2 ? 32 : 16) + srow) * DIMB + gch;

    auto stageA = [&](int tt, int s) {
#pragma unroll
        for (int q = 0; q < 4; ++q)
            load16(gA + (size_t)(q * 8) * DIMB + tt * BKB,
                   &As[s * A_SLOT + wid * 4096 + q * 1024]);
    };
    auto stageB = [&](int tt, int s) {
#pragma unroll
        for (int q = 0; q < 2 * NFR; ++q)
            load16(gB + (size_t)(q * 8) * DIMB + tt * BKB,
                   &Bs[s * B_SLOT + wid * (2 * NFR * 1024) + q * 1024]);
    };

    // ---- fragment read addressing ----
    const int lr = lane & 31, hi2 = (lane >> 5) * 2, swz = lane & 7;

    f32x16 acc[4][NFR];
#pragma unroll
    for (int m = 0; m < 4; ++m)
#pragma unroll
        for (int n = 0; n < NFR; ++n)
#pragma unroll
            for (int r = 0; r < 16; ++r) acc[m][n][r] = 0.0f;

    stageA(0, 0); stageB(0, 0);
    stageA(1, 1); stageB(1, 1);
    waitcnt_vm<CALLS>();
    hard_barrier();

    for (int t = 0; t < NT; ++t) {
        const char* arow = &As[(t & 1) * A_SLOT] + (wr * 128 + lr) * BKB;
        const char* brow = &Bs[(t & 1) * B_SLOT] + (wc * WN + lr) * BKB;

        // K-half 0 (bytes 0..63 of the 128B tile)
        i32x8 a0[4], b0[NFR];
#pragma unroll
        for (int m = 0; m < 4; ++m) a0[m] = rdfrag(arow + m * 32 * BKB, hi2, swz);
#pragma unroll
        for (int n = 0; n < NFR; ++n) b0[n] = rdfrag(brow + n * 32 * BKB, hi2, swz);
        __builtin_amdgcn_s_setprio(1);
#pragma unroll
        for (int m = 0; m < 4; ++m)
#pragma unroll
            for (int n = 0; n < NFR; ++n)
                acc[m][n] = __builtin_amdgcn_mfma_scale_f32_32x32x64_f8f6f4(
                    a0[m], b0[n], acc[m][n], 0, 0, 0, 0x7F7F7F7F, 0, 0x7F7F7F7F);
        __builtin_amdgcn_s_setprio(0);

        // K-half 1 (bytes 64..127) — read before the slot is released
        i32x8 a1[4], b1[NFR];
#pragma unroll
        for (int m = 0; m < 4; ++m) a1[m] = rdfrag(arow + m * 32 * BKB, 4 + hi2, swz);
#pragma unroll
        for (int n = 0; n < NFR; ++n) b1[n] = rdfrag(brow + n * 32 * BKB, 4 + hi2, swz);
        asm volatile("s_waitcnt lgkmcnt(0)" ::: "memory");
        hard_barrier();

        const bool st = (t + 2 < NT);
        if (st) stageA(t + 2, t & 1);
        __builtin_amdgcn_s_setprio(1);
#pragma unroll
        for (int m = 0; m < 2; ++m)
#pragma unroll
            for (int n = 0; n < NFR; ++n)
                acc[m][n] = __builtin_amdgcn_mfma_scale_f32_32x32x64_f8f6f4(
                    a1[m], b1[n], acc[m][n], 0, 0, 0, 0x7F7F7F7F, 0, 0x7F7F7F7F);
        __builtin_amdgcn_s_setprio(0);
        if (st) stageB(t + 2, t & 1);
        __builtin_amdgcn_s_setprio(1);
#pragma unroll
        for (int m = 2; m < 4; ++m)
#pragma unroll
            for (int n = 0; n < NFR; ++n)
                acc[m][n] = __builtin_amdgcn_mfma_scale_f32_32x32x64_f8f6f4(
                    a1[m], b1[n], acc[m][n], 0, 0, 0, 0x7F7F7F7F, 0, 0x7F7F7F7F);
        __builtin_amdgcn_s_setprio(0);

        if (t < NT - 1) {
            if (st) waitcnt_vm<CALLS>(); else waitcnt_vm<0>();
            hard_barrier();
        }
    }

    // ---- epilogue: raw dot = 256*g; exp(-max(2-2g,0)) = exp(min(raw/128 - 2, 0)) ----
    float s = 0.0f;
#pragma unroll
    for (int m = 0; m < 4; ++m)
#pragma unroll
        for (int n = 0; n < NFR; ++n)
#pragma unroll
            for (int r = 0; r < 16; ++r)
                s += __expf(fminf(acc[m][n][r] * (1.0f / 128.0f) - 2.0f, 0.0f));
#pragma unroll
    for (int off = 32; off > 0; off >>= 1) s += __shfl_down(s, off);
    if (lane == 0) red[wid] = s;
    __syncthreads();
    if (tid == 0) {
        float tot = 0.0f;
#pragma unroll
        for (int w = 0; w < 8; ++w) tot += red[w];
        partials[blockIdx.x] = (bi == bj ? 1.0f : 2.0f) * tot;
    }
}

// ---------------- kernel 3: reduce partials, scale ----------------
__global__ __launch_bounds__(256) void finalize(const float* __restrict__ partials,
                                                float* __restrict__ out) {
    float s = 0.f;
    for (int i = threadIdx.x; i < NFULL + 32; i += 256) s += partials[i];
#pragma unroll
    for (int off = 32; off > 0; off >>= 1) s += __shfl_down(s, off);
    __shared__ float red[4];
    if ((threadIdx.x & 63) == 0) red[threadIdx.x >> 6] = s;
    __syncthreads();
    if (threadIdx.x == 0)
        out[0] = (red[0] + red[1] + red[2] + red[3]) *
                 (1.0f / (8191.0f * 8192.0f));
}

extern "C" void kernel_launch(void* const* d_in, const int* in_sizes, int n_in,
                              void* d_out, int out_size, void* d_ws, size_t ws_size,
                              hipStream_t stream) {
    const float* x = (const float*)d_in[0];
    float* out = (float*)d_out;
    char* xq = (char*)d_ws;                                  // 16 MB fp8 matrix
    float* partials = (float*)((char*)d_ws + (size_t)N_CLS * DIMB);

    normalize_rows<<<N_CLS, 256, 0, stream>>>(x, xq);
    gram_tile<2><<<NFULL, 512, 0, stream>>>(xq, partials);
    gram_tile<1><<<32, 512, 0, stream>>>(xq, partials + NFULL);
    finalize<<<1, 256, 0, stream>>>(partials, out);
}

// Round 4
// 74.258 us; speedup vs baseline: 2.8883x; 1.3539x over previous
//
#include <hip/hip_runtime.h>

#define N_CLS 8192
#define DIMB  1024          // bytes per row (fp4: 0.5 B/elem, 2048 elems)
#define BKB   128           // K-tile bytes per row = 256 elements
#define NBT   32            // 8192/256
#define NFULL 512           // full 256x256 tiles in launch 1
#define NT    (DIMB / BKB)  // 8 K-tiles

typedef __attribute__((ext_vector_type(16))) float f32x16;
typedef __attribute__((ext_vector_type(8)))  int   i32x8;

__device__ __forceinline__ void load16(const char* g, char* l) {
    __builtin_amdgcn_global_load_lds(
        (const __attribute__((address_space(1))) void*)g,
        (__attribute__((address_space(3))) void*)l, 16, 0, 0);
}
template <int N> __device__ __forceinline__ void waitcnt_vm() {
    if constexpr (N == 0)      asm volatile("s_waitcnt vmcnt(0)" ::: "memory");
    else if constexpr (N == 6) asm volatile("s_waitcnt vmcnt(6)" ::: "memory");
    else if constexpr (N == 8) asm volatile("s_waitcnt vmcnt(8)" ::: "memory");
}
__device__ __forceinline__ void hard_barrier() {
    __builtin_amdgcn_sched_barrier(0);
    __builtin_amdgcn_s_barrier();
    __builtin_amdgcn_sched_barrier(0);
}

// ---- e2m1 encode: nearest of {0,.5,1,1.5,2,3,4,6} with sign ----
__device__ __forceinline__ unsigned enc1(float v, float sc) {
    float a = fabsf(v) * sc;
    unsigned c = (a >= 0.25f) + (a >= 0.75f) + (a >= 1.25f) + (a >= 1.75f) +
                 (a >= 2.5f)  + (a >= 3.5f)  + (a >= 5.0f);
    return c | ((__float_as_uint(v) >> 28) & 8u);
}
__device__ __forceinline__ unsigned short enc4(float4 v, float sc) {
    return (unsigned short)(enc1(v.x, sc) | (enc1(v.y, sc) << 4) |
                            (enc1(v.z, sc) << 8) | (enc1(v.w, sc) << 12));
}

// ------- kernel 1: wave-per-row L2-normalize, scale x64, quantize to e2m1 -------
__global__ __launch_bounds__(256) void normalize_rows(const float* __restrict__ x,
                                                      unsigned char* __restrict__ xq) {
    const int wid = threadIdx.x >> 6, lane = threadIdx.x & 63;
    const int row = blockIdx.x * 4 + wid;
    const float4* xr = reinterpret_cast<const float4*>(x + (size_t)row * 2048);
    float4 v[8];
    float s = 0.0f;
#pragma unroll
    for (int k = 0; k < 8; ++k) {
        v[k] = xr[lane + 64 * k];
        s += v[k].x*v[k].x + v[k].y*v[k].y + v[k].z*v[k].z + v[k].w*v[k].w;
    }
#pragma unroll
    for (int off = 32; off > 0; off >>= 1) s += __shfl_down(s, off);
    s = __shfl(s, 0);
    const float sc = 64.0f / fmaxf(sqrtf(s), 1e-12f);
    unsigned short* orow = reinterpret_cast<unsigned short*>(xq + (size_t)row * DIMB);
#pragma unroll
    for (int k = 0; k < 8; ++k) orow[lane + 64 * k] = enc4(v[k], sc);
}

// read one 16-byte (K=64, fp4) fragment from a swizzled LDS row; dup into both halves
__device__ __forceinline__ i32x8 rdfrag4(const char* rowp, int cc, int swz) {
    int4 d = *reinterpret_cast<const int4*>(rowp + (((cc) ^ swz) << 4));
    i32x8 r;
    r[0] = d.x; r[1] = d.y; r[2] = d.z; r[3] = d.w;
    r[4] = d.x; r[5] = d.y; r[6] = d.z; r[7] = d.w;
    return r;
}

#define MFMA4(A, B, C) __builtin_amdgcn_mfma_scale_f32_32x32x64_f8f6f4( \
    (A), (B), (C), 4, 4, 0, 0x7F7F7F7F, 0, 0x7F7F7F7F)

// ---- kernel 2: deep-pipelined 256xBN MX-fp4 gram tile + fused exp-sum ----
template <int NFR>   // NFR=2: 256x256 tiles; NFR=1: 256x128 half-tiles of the last 16 tiles
__global__ __launch_bounds__(512, 2) void gram_tile(const char* __restrict__ xq,
                                                    float* __restrict__ partials) {
    constexpr int WN     = NFR * 32;
    constexpr int A_SLOT = 256 * BKB;          // 32 KiB
    constexpr int B_SLOT = NFR * 128 * BKB;    // 32 / 16 KiB
    constexpr int CALLS  = 4 + 2 * NFR;        // global_load_lds per wave per K-tile

    __shared__ __align__(16) char As[2 * A_SLOT];
    __shared__ __align__(16) char Bs[2 * B_SLOT];
    __shared__ float red[8];

    int lin, colHalf;
    if constexpr (NFR == 2) { lin = blockIdx.x; colHalf = 0; }
    else { lin = NFULL + (blockIdx.x >> 1); colHalf = blockIdx.x & 1; }
    int bi = 0, rem = lin;
    while (rem >= NBT - bi) { rem -= NBT - bi; ++bi; }
    const int bj = bi + rem;

    const int tid = threadIdx.x;
    const int lane = tid & 63, wid = tid >> 6;
    const int wr = wid >> 2, wc = wid & 3;     // wave grid 2 x 4

    // ---- staging (pre-swizzled global source; linear LDS dest) ----
    const int srow = lane >> 3;                      // 0..7 within an 8-row call
    const int gch  = ((lane & 7) ^ srow) << 4;       // involutive 16B-chunk XOR
    const char* gA = xq + (size_t)(bi * 256 + wid * 32 + srow) * DIMB + gch;
    const char* gB = xq + (size_t)(bj * 256 + colHalf * 128 +
                                   wid * (NFR == 2 ? 32 : 16) + srow) * DIMB + gch;

    auto stageA = [&](int tt, int s) {
#pragma unroll
        for (int q = 0; q < 4; ++q)
            load16(gA + (size_t)(q * 8) * DIMB + tt * BKB,
                   &As[s * A_SLOT + wid * 4096 + q * 1024]);
    };
    auto stageB = [&](int tt, int s) {
#pragma unroll
        for (int q = 0; q < 2 * NFR; ++q)
            load16(gB + (size_t)(q * 8) * DIMB + tt * BKB,
                   &Bs[s * B_SLOT + wid * (2 * NFR * 1024) + q * 1024]);
    };

    const int lr = lane & 31, hi = lane >> 5, swz = lane & 7;

    f32x16 acc[4][NFR];
#pragma unroll
    for (int m = 0; m < 4; ++m)
#pragma unroll
        for (int n = 0; n < NFR; ++n)
#pragma unroll
            for (int r = 0; r < 16; ++r) acc[m][n][r] = 0.0f;

    stageA(0, 0); stageB(0, 0);
    stageA(1, 1); stageB(1, 1);
    waitcnt_vm<CALLS>();
    hard_barrier();

    for (int t = 0; t < NT; ++t) {
        const char* arow = &As[(t & 1) * A_SLOT] + (wr * 128 + lr) * BKB;
        const char* brow = &Bs[(t & 1) * B_SLOT] + (wc * WN + lr) * BKB;

        // K-slices 0,1 (elements 0..127 of the 256-elem tile)
        i32x8 a0[4], a1[4], b0[NFR], b1[NFR];
#pragma unroll
        for (int m = 0; m < 4; ++m) {
            a0[m] = rdfrag4(arow + m * 32 * BKB, 0 + hi, swz);
            a1[m] = rdfrag4(arow + m * 32 * BKB, 2 + hi, swz);
        }
#pragma unroll
        for (int n = 0; n < NFR; ++n) {
            b0[n] = rdfrag4(brow + n * 32 * BKB, 0 + hi, swz);
            b1[n] = rdfrag4(brow + n * 32 * BKB, 2 + hi, swz);
        }
        __builtin_amdgcn_s_setprio(1);
#pragma unroll
        for (int m = 0; m < 4; ++m)
#pragma unroll
            for (int n = 0; n < NFR; ++n)
                acc[m][n] = MFMA4(a0[m], b0[n], acc[m][n]);
#pragma unroll
        for (int m = 0; m < 4; ++m)
#pragma unroll
            for (int n = 0; n < NFR; ++n)
                acc[m][n] = MFMA4(a1[m], b1[n], acc[m][n]);
        __builtin_amdgcn_s_setprio(0);

        // K-slices 2,3 — read before the slot is released
        i32x8 a2[4], a3[4], b2[NFR], b3[NFR];
#pragma unroll
        for (int m = 0; m < 4; ++m) {
            a2[m] = rdfrag4(arow + m * 32 * BKB, 4 + hi, swz);
            a3[m] = rdfrag4(arow + m * 32 * BKB, 6 + hi, swz);
        }
#pragma unroll
        for (int n = 0; n < NFR; ++n) {
            b2[n] = rdfrag4(brow + n * 32 * BKB, 4 + hi, swz);
            b3[n] = rdfrag4(brow + n * 32 * BKB, 6 + hi, swz);
        }
        asm volatile("s_waitcnt lgkmcnt(0)" ::: "memory");
        hard_barrier();

        const bool st = (t + 2 < NT);
        if (st) stageA(t + 2, t & 1);
        __builtin_amdgcn_s_setprio(1);
#pragma unroll
        for (int m = 0; m < 4; ++m)
#pragma unroll
            for (int n = 0; n < NFR; ++n)
                acc[m][n] = MFMA4(a2[m], b2[n], acc[m][n]);
        __builtin_amdgcn_s_setprio(0);
        if (st) stageB(t + 2, t & 1);
        __builtin_amdgcn_s_setprio(1);
#pragma unroll
        for (int m = 0; m < 4; ++m)
#pragma unroll
            for (int n = 0; n < NFR; ++n)
                acc[m][n] = MFMA4(a3[m], b3[n], acc[m][n]);
        __builtin_amdgcn_s_setprio(0);

        if (t < NT - 1) {
            if (st) waitcnt_vm<CALLS>(); else waitcnt_vm<0>();
            hard_barrier();
        }
    }

    // ---- epilogue: raw dot = 4096*g (S=64); exp(-max(2-2g,0)) = exp(min(raw/2048-2, 0)) ----
    float s = 0.0f;
#pragma unroll
    for (int m = 0; m < 4; ++m)
#pragma unroll
        for (int n = 0; n < NFR; ++n)
#pragma unroll
            for (int r = 0; r < 16; ++r)
                s += __expf(fminf(acc[m][n][r] * (1.0f / 2048.0f) - 2.0f, 0.0f));
#pragma unroll
    for (int off = 32; off > 0; off >>= 1) s += __shfl_down(s, off);
    if (lane == 0) red[wid] = s;
    __syncthreads();
    if (tid == 0) {
        float tot = 0.0f;
#pragma unroll
        for (int w = 0; w < 8; ++w) tot += red[w];
        partials[blockIdx.x] = (bi == bj ? 1.0f : 2.0f) * tot;
    }
}

// ---------------- kernel 3: reduce partials, scale ----------------
__global__ __launch_bounds__(256) void finalize(const float* __restrict__ partials,
                                                float* __restrict__ out) {
    float s = 0.f;
    for (int i = threadIdx.x; i < NFULL + 32; i += 256) s += partials[i];
#pragma unroll
    for (int off = 32; off > 0; off >>= 1) s += __shfl_down(s, off);
    __shared__ float red[4];
    if ((threadIdx.x & 63) == 0) red[threadIdx.x >> 6] = s;
    __syncthreads();
    if (threadIdx.x == 0)
        out[0] = (red[0] + red[1] + red[2] + red[3]) *
                 (1.0f / (8191.0f * 8192.0f));
}

extern "C" void kernel_launch(void* const* d_in, const int* in_sizes, int n_in,
                              void* d_out, int out_size, void* d_ws, size_t ws_size,
                              hipStream_t stream) {
    const float* x = (const float*)d_in[0];
    float* out = (float*)d_out;
    unsigned char* xq = (unsigned char*)d_ws;                // 8 MB fp4 matrix
    float* partials = (float*)((char*)d_ws + (size_t)N_CLS * DIMB);

    normalize_rows<<<N_CLS / 4, 256, 0, stream>>>(x, xq);
    gram_tile<2><<<NFULL, 512, 0, stream>>>((const char*)xq, partials);
    gram_tile<1><<<32, 512, 0, stream>>>((const char*)xq, partials + NFULL);
    finalize<<<1, 256, 0, stream>>>(partials, out);
}